// Round 5
// baseline (135.934 us; speedup 1.0000x reference)
//
#include <hip/hip_runtime.h>
#include <math.h>

// Problem constants (B=4, S=2048, D=1024, O=512, T=16, depth=4)
#define TOK 8192
#define DD  1024
#define OO  512
#define NC  256   // 240 decision rows + 16 gate rows

// ---- workspace byte layout (~1.5MB) ----
// Wc4: [128 k8][256 ncol] 16B units (8 consecutive k as bf16 per unit)
// LO4: [32 k8][512 ocol] 16B units
#define WC4_HI 0
#define WC4_LO (512*1024)
#define LO4_HI (1024*1024)
#define LO4_LO (1280*1024)
#define PAR_B  (1536*1024)   // f32 bias[240], invt[240]

typedef __attribute__((ext_vector_type(8))) short short8;
typedef __attribute__((ext_vector_type(4))) float f32x4;

#define MFMA16(a,b,c) __builtin_amdgcn_mfma_f32_16x16x32_bf16((a),(b),(c),0,0,0)

__device__ __forceinline__ ushort f2bh(float f) {   // f32 -> bf16 RNE
  union { float f; unsigned u; } v; v.f = f;
  unsigned r = v.u + 0x7fffu + ((v.u >> 16) & 1u);
  return (ushort)(r >> 16);
}
__device__ __forceinline__ float bh2f(ushort h) {
  union { unsigned u; float f; } v; v.u = ((unsigned)h) << 16; return v.f;
}
__device__ __forceinline__ void split2(float f, ushort& h, ushort& l) {
  h = f2bh(f);
  l = f2bh(f - bh2f(h));
}

// ---------------------------------------------------------------------------
// Prep. Wc part: LDS tile transpose (fixes 4KB-stride lane reads of round 4).
// Blocks 0..15: Wc tiles [64 ncol x 256 k]; 16..79: LO; 80: params.
// ---------------------------------------------------------------------------
__global__ __launch_bounds__(256) void k_prep(
    const float* __restrict__ dw, const float* __restrict__ db,
    const float* __restrict__ lo_in, const float* __restrict__ gw,
    const float* __restrict__ ntl, char* __restrict__ ws) {
  const int bid = blockIdx.x, tid = threadIdx.x;
  if (bid < 16) {
    __shared__ char pt[65536];           // hi tile 32KB | lo tile 32KB
    const int n0 = (bid & 3) * 64;
    const int k0 = (bid >> 2) * 256;
    const int kl4 = (tid & 63) << 2;     // local k (floats), 0..252
#pragma unroll
    for (int i = 0; i < 16; ++i) {
      const int row = (tid >> 6) + 4 * i;   // 0..63 (wave-contiguous rows)
      const int n = n0 + row;
      float v[4];
      if (n < 240) {
        const float4 t4 = *(const float4*)&dw[(size_t)n * DD + k0 + kl4];
        v[0] = t4.x; v[1] = t4.y; v[2] = t4.z; v[3] = t4.w;
      } else {
        const int t = n - 240;
#pragma unroll
        for (int c = 0; c < 4; ++c) v[c] = gw[(size_t)(k0 + kl4 + c) * 16 + t];
      }
      ushort4 h, l;
      split2(v[0], h.x, l.x); split2(v[1], h.y, l.y);
      split2(v[2], h.z, l.z); split2(v[3], h.w, l.w);
      const int u = kl4 >> 3, half = (kl4 >> 2) & 1;
      const int boff = row * 512 + ((u ^ (row & 31)) << 4) + half * 8;
      *(ushort4*)(pt + boff) = h;
      *(ushort4*)(pt + 32768 + boff) = l;
    }
    __syncthreads();
#pragma unroll
    for (int j = 0; j < 8; ++j) {
      const int u = tid + 256 * j;        // 0..2047
      const int c = u & 63;               // ncol-local (lanes vary -> coalesced)
      const int kk = u >> 6;              // 0..31
      const int src = c * 512 + ((kk ^ (c & 31)) << 4);
      const size_t dst = ((size_t)((k0 >> 3) + kk) * 256 + n0 + c) * 16;
      *(short8*)(ws + WC4_HI + dst) = *(const short8*)(pt + src);
      *(short8*)(ws + WC4_LO + dst) = *(const short8*)(pt + 32768 + src);
    }
  } else if (bid < 80) {                 // LO: both sides coalesced
    const int idx  = (bid - 16) * 256 + tid;   // 0..16383
    const int k8   = idx >> 9;           // 0..31
    const int ocol = idx & 511;
    float v[8];
#pragma unroll
    for (int c = 0; c < 8; ++c) v[c] = lo_in[(size_t)(k8 * 8 + c) * OO + ocol];
    short8 h, l;
#pragma unroll
    for (int e = 0; e < 8; ++e) {
      ushort hh, ll; split2(v[e], hh, ll);
      h[e] = (short)hh; l[e] = (short)ll;
    }
    const size_t o16 = ((size_t)k8 * 512 + ocol) * 16;
    *(short8*)(ws + LO4_HI + o16) = h;
    *(short8*)(ws + LO4_LO + o16) = l;
  } else {
    if (tid < 240) {
      float v = ntl[tid] + 0.5413f;
      float sp = (v > 20.f) ? v : log1pf(expf(v));   // softplus
      float* par = (float*)(ws + PAR_B);
      par[tid]       = db[tid];
      par[240 + tid] = 1.0f / sp;
    }
  }
}

// ---------------------------------------------------------------------------
// Fused MFMA kernel: block = 64 tokens, 512 threads (8 waves), grid 128.
// Halves L2 weight traffic vs 32-token blocks (same 1.5MB read covers 2x M).
// GEMM1: wave owns 32 ncols x 64 tokens. GEMM2: 64 ocols x 64 tokens.
// LDS 128KiB: [0,64K) xs dbuf 2x32K (act f32[64][256] overlays, LN psum 4K)
//             [64K,96K) wf_hi | [96K,128K) wf_lo
// ---------------------------------------------------------------------------
#define XSB(b)  ((b) * 32768)      // per-buffer: HI at +0 (16K), LO at +16384
#define WF_HI   65536
#define WF_LO   98304
#define SM_SZ   131072

__global__ __launch_bounds__(512, 2) void k_fused(
    const float* __restrict__ x, const char* __restrict__ ws,
    const float* __restrict__ gate_b, const float* __restrict__ gamma,
    const float* __restrict__ beta, float* __restrict__ out) {
  __shared__ __align__(16) char sm[SM_SZ];

  const char* wc4_hi = ws + WC4_HI;
  const char* wc4_lo = ws + WC4_LO;
  const char* lo4_hi = ws + LO4_HI;
  const char* lo4_lo = ws + LO4_LO;
  const float* par   = (const float*)(ws + PAR_B);

  const int tid  = threadIdx.x;
  const int wv   = tid >> 6;
  const int lane = tid & 63;
  const int l15  = lane & 15;
  const int kgrp = lane >> 4;        // 0..3
  const int m0   = blockIdx.x * 64;

  // ================= Phase A: GEMM1 =================
  f32x4 acc[4][2];
#pragma unroll
  for (int mt = 0; mt < 4; ++mt)
#pragma unroll
    for (int j = 0; j < 2; ++j) acc[mt][j] = (f32x4){0, 0, 0, 0};
  short8 ah[4], al[4];
  short8 bhE[2], blE[2], bhO[2], blO[2];
  float4 px[4];

  const int xm = tid >> 5;           // 0..15
  const int xk = (tid & 31) << 2;    // 0..124

  auto xload = [&](int CH) {
#pragma unroll
    for (int rr = 0; rr < 4; ++rr)
      px[rr] = *(const float4*)&x[(size_t)(m0 + rr * 16 + xm) * DD + CH * 128 + xk];
  };
  auto xstore = [&](int BUF) {
#pragma unroll
    for (int rr = 0; rr < 4; ++rr) {
      ushort4 h, l;
      split2(px[rr].x, h.x, l.x); split2(px[rr].y, h.y, l.y);
      split2(px[rr].z, h.z, l.z); split2(px[rr].w, h.w, l.w);
      const int row = rr * 16 + xm;
      const int off = (row * 256 + xk * 2) ^ ((row & 7) << 4);
      *(ushort4*)(sm + XSB(BUF) + off) = h;
      *(ushort4*)(sm + XSB(BUF) + 16384 + off) = l;
    }
  };
  auto loadB1 = [&](int F, short8 (&BH)[2], short8 (&BL)[2]) {
    const size_t base = ((size_t)(F * 4 + kgrp) * 256) * 16;
#pragma unroll
    for (int j = 0; j < 2; ++j) {
      const size_t o = base + (size_t)(wv * 32 + j * 16 + l15) * 16;
      BH[j] = *(const short8*)(wc4_hi + o);
      BL[j] = *(const short8*)(wc4_lo + o);
    }
  };
  auto afrag = [&](int CB, int KS) {
    const int k0b = KS * 64 + kgrp * 16;
#pragma unroll
    for (int mt = 0; mt < 4; ++mt) {
      const int row = mt * 16 + l15;
      const int a = (row * 256 + k0b) ^ ((row & 7) << 4);
      ah[mt] = *(const short8*)(sm + XSB(CB) + a);
      al[mt] = *(const short8*)(sm + XSB(CB) + 16384 + a);
    }
  };
  auto mfmaStep = [&](short8 (&BH)[2], short8 (&BL)[2]) {
#pragma unroll
    for (int mt = 0; mt < 4; ++mt)
#pragma unroll
      for (int j = 0; j < 2; ++j) {
        acc[mt][j] = MFMA16(ah[mt], BH[j], acc[mt][j]);
        acc[mt][j] = MFMA16(ah[mt], BL[j], acc[mt][j]);
        acc[mt][j] = MFMA16(al[mt], BH[j], acc[mt][j]);
      }
  };

  // prologue
  xload(0);
  xstore(0);
  loadB1(0, bhE, blE);

  for (int ch = 0; ch < 8; ++ch) {
    __syncthreads();                 // xs(ch) visible to all waves
    const int cb = ch & 1;
    if (ch < 7) xload(ch + 1);       // HBM prefetch, hides under MFMAs
    const int f = ch * 4;
    afrag(cb, 0); loadB1(f + 1, bhO, blO); mfmaStep(bhE, blE);
    afrag(cb, 1); loadB1(f + 2, bhE, blE); mfmaStep(bhO, blO);
    afrag(cb, 2); loadB1(f + 3, bhO, blO); mfmaStep(bhE, blE);
    afrag(cb, 3); loadB1((f + 4 < 32) ? f + 4 : 31, bhE, blE); mfmaStep(bhO, blO);
    if (ch < 7) xstore(cb ^ 1);      // write NEXT buffer
  }
  __syncthreads();

  // scatter logits into act f32[64][256] (overlays xs)
  {
    float* actp = (float*)sm;
#pragma unroll
    for (int mt = 0; mt < 4; ++mt)
#pragma unroll
      for (int j = 0; j < 2; ++j)
#pragma unroll
        for (int r = 0; r < 4; ++r) {
          const int row = mt * 16 + kgrp * 4 + r;
          const int col = wv * 32 + j * 16 + l15;
          actp[row * 256 + col] = acc[mt][j][r];
        }
  }
  __syncthreads();

  // GEMM2 B prologue (reads ws only) — L2 latency hides under epilogue
  short8 cbhE[4], cblE[4], cbhO[4], cblO[4];
  auto loadB2 = [&](int F, short8 (&BH)[4], short8 (&BL)[4]) {
    const size_t base = ((size_t)(F * 4 + kgrp) * 512) * 16;
#pragma unroll
    for (int t = 0; t < 4; ++t) {
      const size_t o = base + (size_t)(wv * 64 + t * 16 + l15) * 16;
      BH[t] = *(const short8*)(lo4_hi + o);
      BL[t] = *(const short8*)(lo4_lo + o);
    }
  };
  loadB2(0, cbhE, cblE);

  // ================= Phase B: forest epilogue (2 tokens/thread) ============
  {
    const float* actp = (const float*)sm;
    const int tr = tid & 15;          // tree
#pragma unroll
    for (int p = 0; p < 2; ++p) {
      const int token = p * 32 + (tid >> 4);   // 0..63
      const float* arow_p = actp + token * 256;

      float dec[15];
#pragma unroll
      for (int i = 0; i < 15; ++i) {
        const int ci = tr * 15 + i;
        const float z = (arow_p[ci] + par[ci]) * par[240 + ci];
        dec[i] = 1.f / (1.f + expf(-z));
      }
      float gl = arow_p[240 + tr] + gate_b[tr];
      float gmax = gl;
#pragma unroll
      for (int msk = 8; msk >= 1; msk >>= 1) gmax = fmaxf(gmax, __shfl_xor(gmax, msk, 16));
      const float ge = expf(gl - gmax);
      float gsum = ge;
#pragma unroll
      for (int msk = 8; msk >= 1; msk >>= 1) gsum += __shfl_xor(gsum, msk, 16);
      const float gate = ge / gsum;

      float lp[16];
#pragma unroll
      for (int l = 0; l < 16; ++l) {
        float pp = gate;
        int node = 0;
#pragma unroll
        for (int d = 0; d < 4; ++d) {
          const int bit = (l >> (3 - d)) & 1;
          pp *= bit ? (1.f - dec[node]) : dec[node];
          node = 2 * node + 1 + bit;
        }
        lp[l] = pp;
      }
      short8 h0, h1, l0, l1;
#pragma unroll
      for (int e = 0; e < 8; ++e) {
        ushort hh, ll;
        split2(lp[e], hh, ll);     h0[e] = (short)hh; l0[e] = (short)ll;
        split2(lp[8 + e], hh, ll); h1[e] = (short)hh; l1[e] = (short)ll;
      }
      const int b0 = (token * 512 + tr * 32) ^ ((token & 7) << 4);
      const int b1 = (token * 512 + tr * 32 + 16) ^ ((token & 7) << 4);
      *(short8*)(sm + WF_HI + b0) = h0;
      *(short8*)(sm + WF_HI + b1) = h1;
      *(short8*)(sm + WF_LO + b0) = l0;
      *(short8*)(sm + WF_LO + b1) = l1;
    }
  }
  __syncthreads();

  // ================= Phase C: GEMM2 =================
  f32x4 acc2[4][4];
#pragma unroll
  for (int mt = 0; mt < 4; ++mt)
#pragma unroll
    for (int t = 0; t < 4; ++t) acc2[mt][t] = (f32x4){0, 0, 0, 0};
  short8 wah[4], wal[4];
  auto wafrag = [&](int FC) {
    const int k0b = FC * 64 + kgrp * 16;
#pragma unroll
    for (int mt = 0; mt < 4; ++mt) {
      const int row = mt * 16 + l15;
      const int a = (row * 512 + k0b) ^ ((row & 7) << 4);
      wah[mt] = *(const short8*)(sm + WF_HI + a);
      wal[mt] = *(const short8*)(sm + WF_LO + a);
    }
  };
  auto mfma2Step = [&](short8 (&BH)[4], short8 (&BL)[4]) {
#pragma unroll
    for (int mt = 0; mt < 4; ++mt)
#pragma unroll
      for (int t = 0; t < 4; ++t) {
        acc2[mt][t] = MFMA16(wah[mt], BH[t], acc2[mt][t]);
        acc2[mt][t] = MFMA16(wah[mt], BL[t], acc2[mt][t]);
        acc2[mt][t] = MFMA16(wal[mt], BH[t], acc2[mt][t]);
      }
  };

#pragma unroll
  for (int it = 0; it < 4; ++it) {
    const int fe = it * 2;
    wafrag(fe);     loadB2(fe + 1, cbhO, cblO);                    mfma2Step(cbhE, cblE);
    wafrag(fe + 1); loadB2((fe + 2 < 8) ? fe + 2 : 7, cbhE, cblE); mfma2Step(cbhO, cblO);
  }

  // ================= Phase D: LayerNorm (in-register) =================
  float* ps = (float*)sm;    // [64 rows][8 waves][2] f32 = 4KB (act dead)
#pragma unroll
  for (int mt = 0; mt < 4; ++mt)
#pragma unroll
    for (int r = 0; r < 4; ++r) {
      float s = 0.f, q = 0.f;
#pragma unroll
      for (int t = 0; t < 4; ++t) {
        const float v = acc2[mt][t][r];
        s += v; q += v * v;
      }
#pragma unroll
      for (int msk = 8; msk >= 1; msk >>= 1) {
        s += __shfl_xor(s, msk, 16);
        q += __shfl_xor(q, msk, 16);
      }
      if (l15 == 0) {
        const int row = mt * 16 + kgrp * 4 + r;
        ps[(row * 8 + wv) * 2 + 0] = s;
        ps[(row * 8 + wv) * 2 + 1] = q;
      }
    }
  __syncthreads();

#pragma unroll
  for (int mt = 0; mt < 4; ++mt)
#pragma unroll
    for (int r = 0; r < 4; ++r) {
      const int row = mt * 16 + kgrp * 4 + r;
      float S = 0.f, Q = 0.f;
#pragma unroll
      for (int p = 0; p < 8; ++p) {
        S += ps[(row * 8 + p) * 2 + 0];
        Q += ps[(row * 8 + p) * 2 + 1];
      }
      const float mu  = S * (1.f / 512.f);
      const float var = Q * (1.f / 512.f) - mu * mu;
      const float rs  = rsqrtf(var + 1e-5f);
#pragma unroll
      for (int t = 0; t < 4; ++t) {
        const int col = wv * 64 + t * 16 + l15;
        out[(size_t)(m0 + row) * OO + col] =
            (acc2[mt][t][r] - mu) * rs * gamma[col] + beta[col];
      }
    }
}

// ---------------------------------------------------------------------------
extern "C" void kernel_launch(void* const* d_in, const int* in_sizes, int n_in,
                              void* d_out, int out_size, void* d_ws, size_t ws_size,
                              hipStream_t stream) {
  const float* x   = (const float*)d_in[0];  // (4,2048,1024)
  const float* dw  = (const float*)d_in[1];  // (16,15,1024)
  const float* db  = (const float*)d_in[2];  // (16,15)
  const float* lo  = (const float*)d_in[3];  // (16,16,512)
  const float* gw  = (const float*)d_in[4];  // (1024,16)
  const float* gb  = (const float*)d_in[5];  // (16,)
  const float* ntl = (const float*)d_in[6];  // (16,15)
  const float* g   = (const float*)d_in[7];  // (512,)
  const float* b   = (const float*)d_in[8];  // (512,)
  char* ws   = (char*)d_ws;
  float* out = (float*)d_out;

  k_prep<<<81, 256, 0, stream>>>(dw, db, lo, gw, ntl, ws);
  k_fused<<<128, 512, 0, stream>>>(x, ws, gb, g, b, out);
}

// Round 8
// 124.254 us; speedup vs baseline: 1.0940x; 1.0940x over previous
//
#include <hip/hip_runtime.h>
#include <math.h>

// Problem constants (B=4, S=2048, D=1024, O=512, T=16, depth=4)
#define TOK 8192
#define DD  1024
#define OO  512
#define NC  256   // 240 decision rows + 16 gate rows

// ---- workspace byte layout (~1.5MB) ----
// Wc4: [128 k8][256 ncol] 16B units (8 consecutive k as bf16 per unit)
// LO4: [32 k8][512 ocol] 16B units
#define WC4_HI 0
#define WC4_LO (512*1024)
#define LO4_HI (1024*1024)
#define LO4_LO (1280*1024)
#define PAR_B  (1536*1024)   // f32 bias[240], invt[240]

typedef __attribute__((ext_vector_type(8))) short short8;
typedef __attribute__((ext_vector_type(4))) float f32x4;

#define MFMA16(a,b,c) __builtin_amdgcn_mfma_f32_16x16x32_bf16((a),(b),(c),0,0,0)

__device__ __forceinline__ ushort f2bh(float f) {   // f32 -> bf16 RNE
  union { float f; unsigned u; } v; v.f = f;
  unsigned r = v.u + 0x7fffu + ((v.u >> 16) & 1u);
  return (ushort)(r >> 16);
}
__device__ __forceinline__ float bh2f(ushort h) {
  union { unsigned u; float f; } v; v.u = ((unsigned)h) << 16; return v.f;
}
__device__ __forceinline__ void split2(float f, ushort& h, ushort& l) {
  h = f2bh(f);
  l = f2bh(f - bh2f(h));
}

// ---------------------------------------------------------------------------
// Prep (coalesced both sides via LDS transpose for Wc).
// ---------------------------------------------------------------------------
__global__ __launch_bounds__(256) void k_prep(
    const float* __restrict__ dw, const float* __restrict__ db,
    const float* __restrict__ lo_in, const float* __restrict__ gw,
    const float* __restrict__ ntl, char* __restrict__ ws) {
  const int bid = blockIdx.x, tid = threadIdx.x;
  if (bid < 16) {
    __shared__ char pt[65536];           // hi tile 32KB | lo tile 32KB
    const int n0 = (bid & 3) * 64;
    const int k0 = (bid >> 2) * 256;
    const int kl4 = (tid & 63) << 2;     // local k (floats), 0..252
#pragma unroll
    for (int i = 0; i < 16; ++i) {
      const int row = (tid >> 6) + 4 * i;   // 0..63
      const int n = n0 + row;
      float v[4];
      if (n < 240) {
        const float4 t4 = *(const float4*)&dw[(size_t)n * DD + k0 + kl4];
        v[0] = t4.x; v[1] = t4.y; v[2] = t4.z; v[3] = t4.w;
      } else {
        const int t = n - 240;
#pragma unroll
        for (int c = 0; c < 4; ++c) v[c] = gw[(size_t)(k0 + kl4 + c) * 16 + t];
      }
      ushort4 h, l;
      split2(v[0], h.x, l.x); split2(v[1], h.y, l.y);
      split2(v[2], h.z, l.z); split2(v[3], h.w, l.w);
      const int u = kl4 >> 3, half = (kl4 >> 2) & 1;
      const int boff = row * 512 + ((u ^ (row & 31)) << 4) + half * 8;
      *(ushort4*)(pt + boff) = h;
      *(ushort4*)(pt + 32768 + boff) = l;
    }
    __syncthreads();
#pragma unroll
    for (int j = 0; j < 8; ++j) {
      const int u = tid + 256 * j;        // 0..2047
      const int c = u & 63;               // ncol-local
      const int kk = u >> 6;              // 0..31
      const int src = c * 512 + ((kk ^ (c & 31)) << 4);
      const size_t dst = ((size_t)((k0 >> 3) + kk) * 256 + n0 + c) * 16;
      *(short8*)(ws + WC4_HI + dst) = *(const short8*)(pt + src);
      *(short8*)(ws + WC4_LO + dst) = *(const short8*)(pt + 32768 + src);
    }
  } else if (bid < 80) {                 // LO: both sides coalesced
    const int idx  = (bid - 16) * 256 + tid;   // 0..16383
    const int k8   = idx >> 9;           // 0..31
    const int ocol = idx & 511;
    float v[8];
#pragma unroll
    for (int c = 0; c < 8; ++c) v[c] = lo_in[(size_t)(k8 * 8 + c) * OO + ocol];
    short8 h, l;
#pragma unroll
    for (int e = 0; e < 8; ++e) {
      ushort hh, ll; split2(v[e], hh, ll);
      h[e] = (short)hh; l[e] = (short)ll;
    }
    const size_t o16 = ((size_t)k8 * 512 + ocol) * 16;
    *(short8*)(ws + LO4_HI + o16) = h;
    *(short8*)(ws + LO4_LO + o16) = l;
  } else {
    if (tid < 240) {
      float v = ntl[tid] + 0.5413f;
      float sp = (v > 20.f) ? v : log1pf(expf(v));   // softplus
      float* par = (float*)(ws + PAR_B);
      par[tid]       = db[tid];
      par[240 + tid] = 1.0f / sp;
    }
  }
}

// ---------------------------------------------------------------------------
// Fused MFMA kernel: block = 32 tokens, 512 threads (8 waves), grid 256.
// GEMM1: wave owns 32 ncols x 32 tokens; B from L2, 4-buffer distance-2.
// GEMM2: wave owns 64 ocols; B from L2, 3-buffer distance-2 (full unroll).
// LDS 64.5KB: xs dbuf 2x16K (act f32[32][256]+psum overlays) | wf hi/lo 16K+16K
// Swizzle: full (row&15)<<4 XOR -> b128 reads hit the 8-access/bank floor.
// ---------------------------------------------------------------------------
#define XSB(b)  ((b) * 16384)      // per-buffer: HI at +0 (8K), LO at +8192
#define WF_HI   32768
#define WF_LO   49152
#define SM_SZ   65536

__global__ __launch_bounds__(512) void k_fused(
    const float* __restrict__ x, const char* __restrict__ ws,
    const float* __restrict__ gate_b, const float* __restrict__ gamma,
    const float* __restrict__ beta, float* __restrict__ out) {
  __shared__ __align__(16) char sm[SM_SZ];

  const char* wc4_hi = ws + WC4_HI;
  const char* wc4_lo = ws + WC4_LO;
  const char* lo4_hi = ws + LO4_HI;
  const char* lo4_lo = ws + LO4_LO;
  const float* par   = (const float*)(ws + PAR_B);

  const int tid  = threadIdx.x;
  const int wv   = tid >> 6;
  const int lane = tid & 63;
  const int l15  = lane & 15;
  const int kgrp = lane >> 4;        // 0..3
  const int m0   = blockIdx.x * 32;

  // ================= Phase A: GEMM1 =================
  f32x4 acc00 = {0,0,0,0}, acc01 = {0,0,0,0}, acc10 = {0,0,0,0}, acc11 = {0,0,0,0};
  short8 ah0, ah1, al0, al1;
  short8 b1h[4][2], b1l[4][2];       // 4-buffer B pipeline (literal idx only)
  float4 pxa, pxb;

  auto xload = [&](int CH) {
    const int m_ = tid >> 5, kl = (tid & 31) << 2;
    pxa = *(const float4*)&x[(size_t)(m0 + m_) * DD + CH * 128 + kl];
    pxb = *(const float4*)&x[(size_t)(m0 + 16 + m_) * DD + CH * 128 + kl];
  };
  auto xstore = [&](int BUF) {
    const int kl2 = ((tid & 31) << 2) * 2;
    ushort4 h, l;
    split2(pxa.x, h.x, l.x); split2(pxa.y, h.y, l.y);
    split2(pxa.z, h.z, l.z); split2(pxa.w, h.w, l.w);
    {
      const int m_ = tid >> 5;
      const int off = (m_ * 256 + kl2) ^ ((m_ & 15) << 4);
      *(ushort4*)(sm + XSB(BUF) + off) = h;
      *(ushort4*)(sm + XSB(BUF) + 8192 + off) = l;
    }
    split2(pxb.x, h.x, l.x); split2(pxb.y, h.y, l.y);
    split2(pxb.z, h.z, l.z); split2(pxb.w, h.w, l.w);
    {
      const int m_ = 16 + (tid >> 5);
      const int off = (m_ * 256 + kl2) ^ ((m_ & 15) << 4);
      *(ushort4*)(sm + XSB(BUF) + off) = h;
      *(ushort4*)(sm + XSB(BUF) + 8192 + off) = l;
    }
  };
#define LOADB1(F, S) do {                                               \
    const int Fc = (F) < 31 ? (F) : 31;                                 \
    const size_t base = ((size_t)(Fc * 4 + kgrp) * 256) * 16;           \
    _Pragma("unroll")                                                   \
    for (int j = 0; j < 2; ++j) {                                       \
      const size_t o = base + (size_t)(wv * 32 + j * 16 + l15) * 16;    \
      b1h[S][j] = *(const short8*)(wc4_hi + o);                         \
      b1l[S][j] = *(const short8*)(wc4_lo + o);                         \
    }                                                                   \
  } while (0)
  auto afrag = [&](int CB, int KS) {
    const int k0 = KS * 64 + kgrp * 16;
    const int a0 = (l15 * 256 + k0) ^ ((l15 & 15) << 4);
    const int a1 = ((16 + l15) * 256 + k0) ^ ((l15 & 15) << 4);
    ah0 = *(const short8*)(sm + XSB(CB) + a0);
    al0 = *(const short8*)(sm + XSB(CB) + 8192 + a0);
    ah1 = *(const short8*)(sm + XSB(CB) + a1);
    al1 = *(const short8*)(sm + XSB(CB) + 8192 + a1);
  };
#define MFMASTEP(S) do {                                                   \
    acc00 = MFMA16(ah0, b1h[S][0], acc00); acc00 = MFMA16(ah0, b1l[S][0], acc00); \
    acc00 = MFMA16(al0, b1h[S][0], acc00);                                 \
    acc01 = MFMA16(ah0, b1h[S][1], acc01); acc01 = MFMA16(ah0, b1l[S][1], acc01); \
    acc01 = MFMA16(al0, b1h[S][1], acc01);                                 \
    acc10 = MFMA16(ah1, b1h[S][0], acc10); acc10 = MFMA16(ah1, b1l[S][0], acc10); \
    acc10 = MFMA16(al1, b1h[S][0], acc10);                                 \
    acc11 = MFMA16(ah1, b1h[S][1], acc11); acc11 = MFMA16(ah1, b1l[S][1], acc11); \
    acc11 = MFMA16(al1, b1h[S][1], acc11);                                 \
  } while (0)

  // prologue
  xload(0);
  xstore(0);
  LOADB1(0, 0);
  LOADB1(1, 1);

  for (int ch = 0; ch < 8; ++ch) {
    __syncthreads();                 // xs(ch) visible to all waves
    const int cb = ch & 1;
    if (ch < 7) xload(ch + 1);       // HBM prefetch, hides under MFMAs
    const int f = ch * 4;
    LOADB1(f + 2, 2); afrag(cb, 0); MFMASTEP(0);
    LOADB1(f + 3, 3); afrag(cb, 1); MFMASTEP(1);
    LOADB1(f + 4, 0); afrag(cb, 2); MFMASTEP(2);
    LOADB1(f + 5, 1); afrag(cb, 3); MFMASTEP(3);
    if (ch < 7) xstore(cb ^ 1);      // write NEXT buffer
  }
  __syncthreads();

  // scatter logits into act f32[32][256] (overlays xs)
  {
    float* actp = (float*)sm;
    const f32x4 a[2][2] = {{acc00, acc01}, {acc10, acc11}};
#pragma unroll
    for (int mi = 0; mi < 2; ++mi)
#pragma unroll
      for (int j = 0; j < 2; ++j)
#pragma unroll
        for (int r = 0; r < 4; ++r) {
          const int row = mi * 16 + kgrp * 4 + r;
          const int col = wv * 32 + j * 16 + l15;
          actp[row * 256 + col] = a[mi][j][r];
        }
  }
  __syncthreads();

  // GEMM2 B pipeline buffers (3-buffer, distance 2, literal idx only)
  short8 c2h[3][4], c2l[3][4];
#define LOADB2(F, S) do {                                               \
    const size_t base = ((size_t)((F) * 4 + kgrp) * 512) * 16;          \
    _Pragma("unroll")                                                   \
    for (int t = 0; t < 4; ++t) {                                       \
      const size_t o = base + (size_t)(wv * 64 + t * 16 + l15) * 16;    \
      c2h[S][t] = *(const short8*)(lo4_hi + o);                         \
      c2l[S][t] = *(const short8*)(lo4_lo + o);                         \
    }                                                                   \
  } while (0)
  LOADB2(0, 0);   // issued before epilogue: L2 latency hides under VALU

  // ================= Phase B: forest epilogue =================
  {
    const float* actp = (const float*)sm;
    const int token = tid >> 4;      // 0..31
    const int tr    = tid & 15;      // tree
    const float* arow_p = actp + token * 256;

    float dec[15];
#pragma unroll
    for (int i = 0; i < 15; ++i) {
      const int ci = tr * 15 + i;
      const float z = (arow_p[ci] + par[ci]) * par[240 + ci];
      dec[i] = 1.f / (1.f + expf(-z));
    }
    float gl = arow_p[240 + tr] + gate_b[tr];
    float gmax = gl;
#pragma unroll
    for (int msk = 8; msk >= 1; msk >>= 1) gmax = fmaxf(gmax, __shfl_xor(gmax, msk, 16));
    const float ge = expf(gl - gmax);
    float gsum = ge;
#pragma unroll
    for (int msk = 8; msk >= 1; msk >>= 1) gsum += __shfl_xor(gsum, msk, 16);
    const float gate = ge / gsum;

    float lp[16];
#pragma unroll
    for (int l = 0; l < 16; ++l) {
      float p = gate;
      int node = 0;
#pragma unroll
      for (int d = 0; d < 4; ++d) {
        const int bit = (l >> (3 - d)) & 1;
        p *= bit ? (1.f - dec[node]) : dec[node];
        node = 2 * node + 1 + bit;
      }
      lp[l] = p;
    }
    short8 h0, h1, l0, l1;
#pragma unroll
    for (int e = 0; e < 8; ++e) {
      ushort hh, ll;
      split2(lp[e], hh, ll);     h0[e] = (short)hh; l0[e] = (short)ll;
      split2(lp[8 + e], hh, ll); h1[e] = (short)hh; l1[e] = (short)ll;
    }
    const int b0 = (token * 512 + tr * 32) ^ ((token & 15) << 4);
    const int b1 = (token * 512 + tr * 32 + 16) ^ ((token & 15) << 4);
    *(short8*)(sm + WF_HI + b0) = h0;
    *(short8*)(sm + WF_HI + b1) = h1;
    *(short8*)(sm + WF_LO + b0) = l0;
    *(short8*)(sm + WF_LO + b1) = l1;
  }
  __syncthreads();

  // ================= Phase C: GEMM2 (8 steps, fully unrolled) =========
  f32x4 ac0[4], ac1[4];
#pragma unroll
  for (int t = 0; t < 4; ++t) { ac0[t] = (f32x4){0,0,0,0}; ac1[t] = (f32x4){0,0,0,0}; }
  short8 wah0, wah1, wal0, wal1;
  auto wafrag = [&](int FC) {
    const int k0 = FC * 64 + kgrp * 16;
    const int a0 = (l15 * 512 + k0) ^ ((l15 & 15) << 4);
    const int a1 = ((16 + l15) * 512 + k0) ^ ((l15 & 15) << 4);
    wah0 = *(const short8*)(sm + WF_HI + a0);
    wal0 = *(const short8*)(sm + WF_LO + a0);
    wah1 = *(const short8*)(sm + WF_HI + a1);
    wal1 = *(const short8*)(sm + WF_LO + a1);
  };
#define MFMA2STEP(S) do {                                                  \
    _Pragma("unroll")                                                      \
    for (int t = 0; t < 4; ++t) {                                          \
      ac0[t] = MFMA16(wah0, c2h[S][t], ac0[t]);                            \
      ac0[t] = MFMA16(wah0, c2l[S][t], ac0[t]);                            \
      ac0[t] = MFMA16(wal0, c2h[S][t], ac0[t]);                            \
      ac1[t] = MFMA16(wah1, c2h[S][t], ac1[t]);                            \
      ac1[t] = MFMA16(wah1, c2l[S][t], ac1[t]);                            \
      ac1[t] = MFMA16(wal1, c2h[S][t], ac1[t]);                            \
    }                                                                      \
  } while (0)

  LOADB2(1, 1);
  LOADB2(2, 2); wafrag(0); MFMA2STEP(0);
  LOADB2(3, 0); wafrag(1); MFMA2STEP(1);
  LOADB2(4, 1); wafrag(2); MFMA2STEP(2);
  LOADB2(5, 2); wafrag(3); MFMA2STEP(0);
  LOADB2(6, 0); wafrag(4); MFMA2STEP(1);
  LOADB2(7, 1); wafrag(5); MFMA2STEP(2);
  wafrag(6); MFMA2STEP(0);
  wafrag(7); MFMA2STEP(1);

  // ================= Phase D: LayerNorm (in-register) =================
  float* ps = (float*)sm;    // [32 rows][8 waves][2] f32 = 2KB (act dead)
#pragma unroll
  for (int mi = 0; mi < 2; ++mi)
#pragma unroll
    for (int r = 0; r < 4; ++r) {
      float s = 0.f, q = 0.f;
#pragma unroll
      for (int t = 0; t < 4; ++t) {
        const float v = (mi == 0) ? ac0[t][r] : ac1[t][r];
        s += v; q += v * v;
      }
#pragma unroll
      for (int msk = 8; msk >= 1; msk >>= 1) {
        s += __shfl_xor(s, msk, 16);
        q += __shfl_xor(q, msk, 16);
      }
      if (l15 == 0) {
        const int row = mi * 16 + kgrp * 4 + r;
        ps[(row * 8 + wv) * 2 + 0] = s;
        ps[(row * 8 + wv) * 2 + 1] = q;
      }
    }
  __syncthreads();

#pragma unroll
  for (int mi = 0; mi < 2; ++mi)
#pragma unroll
    for (int r = 0; r < 4; ++r) {
      const int row = mi * 16 + kgrp * 4 + r;
      float S = 0.f, Q = 0.f;
#pragma unroll
      for (int p = 0; p < 8; ++p) {
        S += ps[(row * 8 + p) * 2 + 0];
        Q += ps[(row * 8 + p) * 2 + 1];
      }
      const float mu  = S * (1.f / 512.f);
      const float var = Q * (1.f / 512.f) - mu * mu;
      const float rs  = rsqrtf(var + 1e-5f);
#pragma unroll
      for (int t = 0; t < 4; ++t) {
        const int col = wv * 64 + t * 16 + l15;
        const float v = (mi == 0) ? ac0[t][r] : ac1[t][r];
        out[(size_t)(m0 + row) * OO + col] = (v - mu) * rs * gamma[col] + beta[col];
      }
    }
}

// ---------------------------------------------------------------------------
extern "C" void kernel_launch(void* const* d_in, const int* in_sizes, int n_in,
                              void* d_out, int out_size, void* d_ws, size_t ws_size,
                              hipStream_t stream) {
  const float* x   = (const float*)d_in[0];  // (4,2048,1024)
  const float* dw  = (const float*)d_in[1];  // (16,15,1024)
  const float* db  = (const float*)d_in[2];  // (16,15)
  const float* lo  = (const float*)d_in[3];  // (16,16,512)
  const float* gw  = (const float*)d_in[4];  // (1024,16)
  const float* gb  = (const float*)d_in[5];  // (16,)
  const float* ntl = (const float*)d_in[6];  // (16,15)
  const float* g   = (const float*)d_in[7];  // (512,)
  const float* b   = (const float*)d_in[8];  // (512,)
  char* ws   = (char*)d_ws;
  float* out = (float*)d_out;

  k_prep<<<81, 256, 0, stream>>>(dw, db, lo, gw, ntl, ws);
  k_fused<<<256, 512, 0, stream>>>(x, ws, gb, g, b, out);
}

// Round 9
// 124.133 us; speedup vs baseline: 1.0951x; 1.0010x over previous
//
#include <hip/hip_runtime.h>
#include <math.h>

// Problem constants (B=4, S=2048, D=1024, O=512, T=16, depth=4)
#define TOK 8192
#define DD  1024
#define OO  512
#define NC  256   // 240 decision rows + 16 gate rows

// ---- workspace byte layout (~1.5MB) ----
// Wc4: [128 k8][256 ncol] 16B units (8 consecutive k as bf16 per unit)
// LO4: [32 k8][512 ocol] 16B units
#define WC4_HI 0
#define WC4_LO (512*1024)
#define LO4_HI (1024*1024)
#define LO4_LO (1280*1024)
#define PAR_B  (1536*1024)   // f32 bias[240], invt[240]

typedef __attribute__((ext_vector_type(8))) short short8;
typedef __attribute__((ext_vector_type(4))) float f32x4;

#define MFMA16(a,b,c) __builtin_amdgcn_mfma_f32_16x16x32_bf16((a),(b),(c),0,0,0)

__device__ __forceinline__ ushort f2bh(float f) {   // f32 -> bf16 RNE
  union { float f; unsigned u; } v; v.f = f;
  unsigned r = v.u + 0x7fffu + ((v.u >> 16) & 1u);
  return (ushort)(r >> 16);
}
__device__ __forceinline__ float bh2f(ushort h) {
  union { unsigned u; float f; } v; v.u = ((unsigned)h) << 16; return v.f;
}
__device__ __forceinline__ void split2(float f, ushort& h, ushort& l) {
  h = f2bh(f);
  l = f2bh(f - bh2f(h));
}

// ---------------------------------------------------------------------------
// Prep (byte-identical to round 8 for attribution).
// ---------------------------------------------------------------------------
__global__ __launch_bounds__(256) void k_prep(
    const float* __restrict__ dw, const float* __restrict__ db,
    const float* __restrict__ lo_in, const float* __restrict__ gw,
    const float* __restrict__ ntl, char* __restrict__ ws) {
  const int bid = blockIdx.x, tid = threadIdx.x;
  if (bid < 16) {
    __shared__ char pt[65536];           // hi tile 32KB | lo tile 32KB
    const int n0 = (bid & 3) * 64;
    const int k0 = (bid >> 2) * 256;
    const int kl4 = (tid & 63) << 2;     // local k (floats), 0..252
#pragma unroll
    for (int i = 0; i < 16; ++i) {
      const int row = (tid >> 6) + 4 * i;   // 0..63
      const int n = n0 + row;
      float v[4];
      if (n < 240) {
        const float4 t4 = *(const float4*)&dw[(size_t)n * DD + k0 + kl4];
        v[0] = t4.x; v[1] = t4.y; v[2] = t4.z; v[3] = t4.w;
      } else {
        const int t = n - 240;
#pragma unroll
        for (int c = 0; c < 4; ++c) v[c] = gw[(size_t)(k0 + kl4 + c) * 16 + t];
      }
      ushort4 h, l;
      split2(v[0], h.x, l.x); split2(v[1], h.y, l.y);
      split2(v[2], h.z, l.z); split2(v[3], h.w, l.w);
      const int u = kl4 >> 3, half = (kl4 >> 2) & 1;
      const int boff = row * 512 + ((u ^ (row & 31)) << 4) + half * 8;
      *(ushort4*)(pt + boff) = h;
      *(ushort4*)(pt + 32768 + boff) = l;
    }
    __syncthreads();
#pragma unroll
    for (int j = 0; j < 8; ++j) {
      const int u = tid + 256 * j;        // 0..2047
      const int c = u & 63;               // ncol-local
      const int kk = u >> 6;              // 0..31
      const int src = c * 512 + ((kk ^ (c & 31)) << 4);
      const size_t dst = ((size_t)((k0 >> 3) + kk) * 256 + n0 + c) * 16;
      *(short8*)(ws + WC4_HI + dst) = *(const short8*)(pt + src);
      *(short8*)(ws + WC4_LO + dst) = *(const short8*)(pt + 32768 + src);
    }
  } else if (bid < 80) {                 // LO: both sides coalesced
    const int idx  = (bid - 16) * 256 + tid;   // 0..16383
    const int k8   = idx >> 9;           // 0..31
    const int ocol = idx & 511;
    float v[8];
#pragma unroll
    for (int c = 0; c < 8; ++c) v[c] = lo_in[(size_t)(k8 * 8 + c) * OO + ocol];
    short8 h, l;
#pragma unroll
    for (int e = 0; e < 8; ++e) {
      ushort hh, ll; split2(v[e], hh, ll);
      h[e] = (short)hh; l[e] = (short)ll;
    }
    const size_t o16 = ((size_t)k8 * 512 + ocol) * 16;
    *(short8*)(ws + LO4_HI + o16) = h;
    *(short8*)(ws + LO4_LO + o16) = l;
  } else {
    if (tid < 240) {
      float v = ntl[tid] + 0.5413f;
      float sp = (v > 20.f) ? v : log1pf(expf(v));   // softplus
      float* par = (float*)(ws + PAR_B);
      par[tid]       = db[tid];
      par[240 + tid] = 1.0f / sp;
    }
  }
}

// ---------------------------------------------------------------------------
// Fused MFMA kernel: block = 32 tokens, 1024 threads (16 waves), grid 256.
// Same M=32 tile (L2 weight traffic unchanged) but 2x wave-slots: 4 waves/SIMD
// so L2 load latency is hidden by TLP, not just compile-time prefetch.
// GEMM1: wave owns 16 ncols; GEMM2: wave owns 32 ocols. VGPR target <=128.
// LDS 64KB: xs dbuf 2x16K (act f32[32][256]+psum overlays) | wf hi/lo 16K+16K
// ---------------------------------------------------------------------------
#define XSB(b)  ((b) * 16384)      // per-buffer: HI at +0 (8K), LO at +8192
#define WF_HI   32768
#define WF_LO   49152
#define SM_SZ   65536

__global__ __launch_bounds__(1024) void k_fused(
    const float* __restrict__ x, const char* __restrict__ ws,
    const float* __restrict__ gate_b, const float* __restrict__ gamma,
    const float* __restrict__ beta, float* __restrict__ out) {
  __shared__ __align__(16) char sm[SM_SZ];

  const char* wc4_hi = ws + WC4_HI;
  const char* wc4_lo = ws + WC4_LO;
  const char* lo4_hi = ws + LO4_HI;
  const char* lo4_lo = ws + LO4_LO;
  const float* par   = (const float*)(ws + PAR_B);

  const int tid  = threadIdx.x;        // 0..1023
  const int wv   = tid >> 6;           // 0..15
  const int lane = tid & 63;
  const int l15  = lane & 15;
  const int kgrp = lane >> 4;          // 0..3
  const int m0   = blockIdx.x * 32;

  // ================= Phase A: GEMM1 =================
  f32x4 acc00 = {0,0,0,0}, acc10 = {0,0,0,0};
  short8 ah0, ah1, al0, al1;
  short8 b1h[4], b1l[4];               // 4-buffer B pipeline, 1 ncol/wave
  float4 px;

  const int xm = tid >> 5;             // 0..31
  const int xk = (tid & 31) << 2;      // 0..124

  auto xload = [&](int CH) {
    px = *(const float4*)&x[(size_t)(m0 + xm) * DD + CH * 128 + xk];
  };
  auto xstore = [&](int BUF) {
    ushort4 h, l;
    split2(px.x, h.x, l.x); split2(px.y, h.y, l.y);
    split2(px.z, h.z, l.z); split2(px.w, h.w, l.w);
    const int off = (xm * 256 + xk * 2) ^ ((xm & 15) << 4);
    *(ushort4*)(sm + XSB(BUF) + off) = h;
    *(ushort4*)(sm + XSB(BUF) + 8192 + off) = l;
  };
#define LOADB1(F, S) do {                                               \
    const int Fc = (F) < 31 ? (F) : 31;                                 \
    const size_t o = ((size_t)(Fc * 4 + kgrp) * 256 + wv * 16 + l15) * 16; \
    b1h[S] = *(const short8*)(wc4_hi + o);                              \
    b1l[S] = *(const short8*)(wc4_lo + o);                              \
  } while (0)
  auto afrag = [&](int CB, int KS) {
    const int k0 = KS * 64 + kgrp * 16;
    const int a0 = (l15 * 256 + k0) ^ (l15 << 4);
    const int a1 = ((16 + l15) * 256 + k0) ^ (l15 << 4);
    ah0 = *(const short8*)(sm + XSB(CB) + a0);
    al0 = *(const short8*)(sm + XSB(CB) + 8192 + a0);
    ah1 = *(const short8*)(sm + XSB(CB) + a1);
    al1 = *(const short8*)(sm + XSB(CB) + 8192 + a1);
  };
#define MFMASTEP(S) do {                                                \
    acc00 = MFMA16(ah0, b1h[S], acc00);                                 \
    acc00 = MFMA16(ah0, b1l[S], acc00);                                 \
    acc00 = MFMA16(al0, b1h[S], acc00);                                 \
    acc10 = MFMA16(ah1, b1h[S], acc10);                                 \
    acc10 = MFMA16(ah1, b1l[S], acc10);                                 \
    acc10 = MFMA16(al1, b1h[S], acc10);                                 \
  } while (0)

  // prologue
  xload(0);
  xstore(0);
  LOADB1(0, 0);
  LOADB1(1, 1);

  for (int ch = 0; ch < 8; ++ch) {
    __syncthreads();                 // xs(ch) visible to all waves
    const int cb = ch & 1;
    if (ch < 7) xload(ch + 1);       // HBM prefetch, hides under MFMAs
    const int f = ch * 4;
    LOADB1(f + 2, 2); afrag(cb, 0); MFMASTEP(0);
    LOADB1(f + 3, 3); afrag(cb, 1); MFMASTEP(1);
    LOADB1(f + 4, 0); afrag(cb, 2); MFMASTEP(2);
    LOADB1(f + 5, 1); afrag(cb, 3); MFMASTEP(3);
    if (ch < 7) xstore(cb ^ 1);      // write NEXT buffer
  }
  __syncthreads();

  // scatter logits into act f32[32][256] (overlays xs)
  {
    float* actp = (float*)sm;
    const int col = wv * 16 + l15;
#pragma unroll
    for (int r = 0; r < 4; ++r) {
      actp[(kgrp * 4 + r) * 256 + col]      = acc00[r];
      actp[(16 + kgrp * 4 + r) * 256 + col] = acc10[r];
    }
  }
  __syncthreads();

  // GEMM2 B pipeline buffers (3-buffer, distance 2, 2 ocol-frags/wave)
  short8 c2h[3][2], c2l[3][2];
#define LOADB2(F, S) do {                                               \
    const size_t base = ((size_t)((F) * 4 + kgrp) * 512) * 16;          \
    _Pragma("unroll")                                                   \
    for (int t = 0; t < 2; ++t) {                                       \
      const size_t o = base + (size_t)(wv * 32 + t * 16 + l15) * 16;    \
      c2h[S][t] = *(const short8*)(lo4_hi + o);                         \
      c2l[S][t] = *(const short8*)(lo4_lo + o);                         \
    }                                                                   \
  } while (0)
  LOADB2(0, 0);   // issued before epilogue: L2 latency hides under VALU
  LOADB2(1, 1);

  // ================= Phase B: forest epilogue (waves 0-7) =============
  if (tid < 512) {
    const float* actp = (const float*)sm;
    const int token = tid >> 4;      // 0..31
    const int tr    = tid & 15;      // tree
    const float* arow_p = actp + token * 256;

    float dec[15];
#pragma unroll
    for (int i = 0; i < 15; ++i) {
      const int ci = tr * 15 + i;
      const float z = (arow_p[ci] + par[ci]) * par[240 + ci];
      dec[i] = 1.f / (1.f + expf(-z));
    }
    float gl = arow_p[240 + tr] + gate_b[tr];
    float gmax = gl;
#pragma unroll
    for (int msk = 8; msk >= 1; msk >>= 1) gmax = fmaxf(gmax, __shfl_xor(gmax, msk, 16));
    const float ge = expf(gl - gmax);
    float gsum = ge;
#pragma unroll
    for (int msk = 8; msk >= 1; msk >>= 1) gsum += __shfl_xor(gsum, msk, 16);
    const float gate = ge / gsum;

    float lp[16];
#pragma unroll
    for (int l = 0; l < 16; ++l) {
      float p = gate;
      int node = 0;
#pragma unroll
      for (int d = 0; d < 4; ++d) {
        const int bit = (l >> (3 - d)) & 1;
        p *= bit ? (1.f - dec[node]) : dec[node];
        node = 2 * node + 1 + bit;
      }
      lp[l] = p;
    }
    short8 h0, h1, l0, l1;
#pragma unroll
    for (int e = 0; e < 8; ++e) {
      ushort hh, ll;
      split2(lp[e], hh, ll);     h0[e] = (short)hh; l0[e] = (short)ll;
      split2(lp[8 + e], hh, ll); h1[e] = (short)hh; l1[e] = (short)ll;
    }
    const int b0 = (token * 512 + tr * 32) ^ ((token & 15) << 4);
    const int b1 = (token * 512 + tr * 32 + 16) ^ ((token & 15) << 4);
    *(short8*)(sm + WF_HI + b0) = h0;
    *(short8*)(sm + WF_HI + b1) = h1;
    *(short8*)(sm + WF_LO + b0) = l0;
    *(short8*)(sm + WF_LO + b1) = l1;
  }
  __syncthreads();

  // ================= Phase C: GEMM2 (8 steps, fully unrolled) =========
  f32x4 ac0[2], ac1[2];
#pragma unroll
  for (int t = 0; t < 2; ++t) { ac0[t] = (f32x4){0,0,0,0}; ac1[t] = (f32x4){0,0,0,0}; }
  short8 wah0, wah1, wal0, wal1;
  auto wafrag = [&](int FC) {
    const int k0 = FC * 64 + kgrp * 16;
    const int a0 = (l15 * 512 + k0) ^ (l15 << 4);
    const int a1 = ((16 + l15) * 512 + k0) ^ (l15 << 4);
    wah0 = *(const short8*)(sm + WF_HI + a0);
    wal0 = *(const short8*)(sm + WF_LO + a0);
    wah1 = *(const short8*)(sm + WF_HI + a1);
    wal1 = *(const short8*)(sm + WF_LO + a1);
  };
#define MFMA2STEP(S) do {                                               \
    _Pragma("unroll")                                                   \
    for (int t = 0; t < 2; ++t) {                                       \
      ac0[t] = MFMA16(wah0, c2h[S][t], ac0[t]);                         \
      ac0[t] = MFMA16(wah0, c2l[S][t], ac0[t]);                         \
      ac0[t] = MFMA16(wal0, c2h[S][t], ac0[t]);                         \
      ac1[t] = MFMA16(wah1, c2h[S][t], ac1[t]);                         \
      ac1[t] = MFMA16(wah1, c2l[S][t], ac1[t]);                         \
      ac1[t] = MFMA16(wal1, c2h[S][t], ac1[t]);                         \
    }                                                                   \
  } while (0)

  LOADB2(2, 2); wafrag(0); MFMA2STEP(0);
  LOADB2(3, 0); wafrag(1); MFMA2STEP(1);
  LOADB2(4, 1); wafrag(2); MFMA2STEP(2);
  LOADB2(5, 2); wafrag(3); MFMA2STEP(0);
  LOADB2(6, 0); wafrag(4); MFMA2STEP(1);
  LOADB2(7, 1); wafrag(5); MFMA2STEP(2);
  wafrag(6); MFMA2STEP(0);
  wafrag(7); MFMA2STEP(1);

  // ================= Phase D: LayerNorm (in-register) =================
  float* ps = (float*)sm;    // [32 rows][16 waves][2] f32 = 4KB (act dead)
#pragma unroll
  for (int mi = 0; mi < 2; ++mi)
#pragma unroll
    for (int r = 0; r < 4; ++r) {
      float s = 0.f, q = 0.f;
#pragma unroll
      for (int t = 0; t < 2; ++t) {
        const float v = (mi == 0) ? ac0[t][r] : ac1[t][r];
        s += v; q += v * v;
      }
#pragma unroll
      for (int msk = 8; msk >= 1; msk >>= 1) {
        s += __shfl_xor(s, msk, 16);
        q += __shfl_xor(q, msk, 16);
      }
      if (l15 == 0) {
        const int row = mi * 16 + kgrp * 4 + r;
        ps[(row * 16 + wv) * 2 + 0] = s;
        ps[(row * 16 + wv) * 2 + 1] = q;
      }
    }
  __syncthreads();

#pragma unroll
  for (int mi = 0; mi < 2; ++mi)
#pragma unroll
    for (int r = 0; r < 4; ++r) {
      const int row = mi * 16 + kgrp * 4 + r;
      float S = 0.f, Q = 0.f;
#pragma unroll
      for (int p = 0; p < 16; ++p) {
        S += ps[(row * 16 + p) * 2 + 0];
        Q += ps[(row * 16 + p) * 2 + 1];
      }
      const float mu  = S * (1.f / 512.f);
      const float var = Q * (1.f / 512.f) - mu * mu;
      const float rs  = rsqrtf(var + 1e-5f);
#pragma unroll
      for (int t = 0; t < 2; ++t) {
        const int col = wv * 32 + t * 16 + l15;
        const float v = (mi == 0) ? ac0[t][r] : ac1[t][r];
        out[(size_t)(m0 + row) * OO + col] = (v - mu) * rs * gamma[col] + beta[col];
      }
    }
}

// ---------------------------------------------------------------------------
extern "C" void kernel_launch(void* const* d_in, const int* in_sizes, int n_in,
                              void* d_out, int out_size, void* d_ws, size_t ws_size,
                              hipStream_t stream) {
  const float* x   = (const float*)d_in[0];  // (4,2048,1024)
  const float* dw  = (const float*)d_in[1];  // (16,15,1024)
  const float* db  = (const float*)d_in[2];  // (16,15)
  const float* lo  = (const float*)d_in[3];  // (16,16,512)
  const float* gw  = (const float*)d_in[4];  // (1024,16)
  const float* gb  = (const float*)d_in[5];  // (16,)
  const float* ntl = (const float*)d_in[6];  // (16,15)
  const float* g   = (const float*)d_in[7];  // (512,)
  const float* b   = (const float*)d_in[8];  // (512,)
  char* ws   = (char*)d_ws;
  float* out = (float*)d_out;

  k_prep<<<81, 256, 0, stream>>>(dw, db, lo, gw, ntl, ws);
  k_fused<<<256, 1024, 0, stream>>>(x, ws, gb, g, b, out);
}

// Round 10
// 123.939 us; speedup vs baseline: 1.0968x; 1.0016x over previous
//
#include <hip/hip_runtime.h>
#include <math.h>

// Problem constants (B=4, S=2048, D=1024, O=512, T=16, depth=4)
#define TOK 8192
#define DD  1024
#define OO  512
#define NC  256   // 240 decision rows + 16 gate rows

// ---- workspace byte layout (~1.5MB) ----
// Wc4: [128 k8][256 ncol] 16B units (8 consecutive k as bf16 per unit)
// LO4: [32 k8][512 ocol] 16B units
#define WC4_HI 0
#define WC4_LO (512*1024)
#define LO4_HI (1024*1024)
#define LO4_LO (1280*1024)
#define PAR_B  (1536*1024)   // f32 bias[240], invt[240]

typedef __attribute__((ext_vector_type(8))) short short8;
typedef __attribute__((ext_vector_type(4))) float f32x4;

#define MFMA16(a,b,c) __builtin_amdgcn_mfma_f32_16x16x32_bf16((a),(b),(c),0,0,0)

__device__ __forceinline__ ushort f2bh(float f) {   // f32 -> bf16 RNE
  union { float f; unsigned u; } v; v.f = f;
  unsigned r = v.u + 0x7fffu + ((v.u >> 16) & 1u);
  return (ushort)(r >> 16);
}
__device__ __forceinline__ float bh2f(ushort h) {
  union { unsigned u; float f; } v; v.u = ((unsigned)h) << 16; return v.f;
}
__device__ __forceinline__ void split2(float f, ushort& h, ushort& l) {
  h = f2bh(f);
  l = f2bh(f - bh2f(h));
}

// ---------------------------------------------------------------------------
// Prep: same algorithm as r8/r9 but 33 blocks x 1024 threads (4x parallelism,
// shorter serial segment before k_fused can start).
// ---------------------------------------------------------------------------
__global__ __launch_bounds__(1024) void k_prep(
    const float* __restrict__ dw, const float* __restrict__ db,
    const float* __restrict__ lo_in, const float* __restrict__ gw,
    const float* __restrict__ ntl, char* __restrict__ ws) {
  const int bid = blockIdx.x, tid = threadIdx.x;
  if (bid < 16) {
    __shared__ char pt[65536];           // hi tile 32KB | lo tile 32KB
    const int n0 = (bid & 3) * 64;
    const int k0 = (bid >> 2) * 256;
    const int kl4 = (tid & 63) << 2;     // local k (floats), 0..252
#pragma unroll
    for (int i = 0; i < 4; ++i) {
      const int row = (tid >> 6) + 16 * i;   // 0..63
      const int n = n0 + row;
      float v[4];
      if (n < 240) {
        const float4 t4 = *(const float4*)&dw[(size_t)n * DD + k0 + kl4];
        v[0] = t4.x; v[1] = t4.y; v[2] = t4.z; v[3] = t4.w;
      } else {
        const int t = n - 240;
#pragma unroll
        for (int c = 0; c < 4; ++c) v[c] = gw[(size_t)(k0 + kl4 + c) * 16 + t];
      }
      ushort4 h, l;
      split2(v[0], h.x, l.x); split2(v[1], h.y, l.y);
      split2(v[2], h.z, l.z); split2(v[3], h.w, l.w);
      const int u = kl4 >> 3, half = (kl4 >> 2) & 1;
      const int boff = row * 512 + ((u ^ (row & 31)) << 4) + half * 8;
      *(ushort4*)(pt + boff) = h;
      *(ushort4*)(pt + 32768 + boff) = l;
    }
    __syncthreads();
#pragma unroll
    for (int j = 0; j < 2; ++j) {
      const int u = tid + 1024 * j;       // 0..2047
      const int c = u & 63;               // ncol-local
      const int kk = u >> 6;              // 0..31
      const int src = c * 512 + ((kk ^ (c & 31)) << 4);
      const size_t dst = ((size_t)((k0 >> 3) + kk) * 256 + n0 + c) * 16;
      *(short8*)(ws + WC4_HI + dst) = *(const short8*)(pt + src);
      *(short8*)(ws + WC4_LO + dst) = *(const short8*)(pt + 32768 + src);
    }
  } else if (bid < 32) {                 // LO: both sides coalesced
    const int idx  = (bid - 16) * 1024 + tid;   // 0..16383
    const int k8   = idx >> 9;           // 0..31
    const int ocol = idx & 511;
    float v[8];
#pragma unroll
    for (int c = 0; c < 8; ++c) v[c] = lo_in[(size_t)(k8 * 8 + c) * OO + ocol];
    short8 h, l;
#pragma unroll
    for (int e = 0; e < 8; ++e) {
      ushort hh, ll; split2(v[e], hh, ll);
      h[e] = (short)hh; l[e] = (short)ll;
    }
    const size_t o16 = ((size_t)k8 * 512 + ocol) * 16;
    *(short8*)(ws + LO4_HI + o16) = h;
    *(short8*)(ws + LO4_LO + o16) = l;
  } else {
    if (tid < 240) {
      float v = ntl[tid] + 0.5413f;
      float sp = (v > 20.f) ? v : log1pf(expf(v));   // softplus
      float* par = (float*)(ws + PAR_B);
      par[tid]       = db[tid];
      par[240 + tid] = 1.0f / sp;
    }
  }
}

// ---------------------------------------------------------------------------
// Fused MFMA kernel: block = 32 tokens, 1024 threads (16 waves), grid 256.
// NEW vs r9: full x tile preloaded+converted to registers at kernel start
// (8 indep HBM loads, max MLP) -> the K-loop's barrier vmcnt drains cover
// only short L2 B-loads + LDS, never HBM latency.  Chunk loop fully
// unrolled so pxh[ch]/pxl[ch] indices are compile-time (no scratch).
// LDS 64KB: xs dbuf 2x16K (act f32[32][256]+psum overlays) | wf hi/lo 16K+16K
// ---------------------------------------------------------------------------
#define XSB(b)  ((b) * 16384)      // per-buffer: HI at +0 (8K), LO at +8192
#define WF_HI   32768
#define WF_LO   49152
#define SM_SZ   65536

__global__ __launch_bounds__(1024) void k_fused(
    const float* __restrict__ x, const char* __restrict__ ws,
    const float* __restrict__ gate_b, const float* __restrict__ gamma,
    const float* __restrict__ beta, float* __restrict__ out) {
  __shared__ __align__(16) char sm[SM_SZ];

  const char* wc4_hi = ws + WC4_HI;
  const char* wc4_lo = ws + WC4_LO;
  const char* lo4_hi = ws + LO4_HI;
  const char* lo4_lo = ws + LO4_LO;
  const float* par   = (const float*)(ws + PAR_B);

  const int tid  = threadIdx.x;        // 0..1023
  const int wv   = tid >> 6;           // 0..15
  const int lane = tid & 63;
  const int l15  = lane & 15;
  const int kgrp = lane >> 4;          // 0..3
  const int m0   = blockIdx.x * 32;

  const int xm = tid >> 5;             // 0..31
  const int xk = (tid & 31) << 2;      // 0..124

  // ---- x preload: all 8 chunks to registers, convert once ----
  ushort4 pxh[8], pxl[8];
  {
    float4 t[8];
#pragma unroll
    for (int ch = 0; ch < 8; ++ch)
      t[ch] = *(const float4*)&x[(size_t)(m0 + xm) * DD + ch * 128 + xk];
#pragma unroll
    for (int ch = 0; ch < 8; ++ch) {
      split2(t[ch].x, pxh[ch].x, pxl[ch].x);
      split2(t[ch].y, pxh[ch].y, pxl[ch].y);
      split2(t[ch].z, pxh[ch].z, pxl[ch].z);
      split2(t[ch].w, pxh[ch].w, pxl[ch].w);
    }
  }

  // ================= Phase A: GEMM1 =================
  f32x4 acc00 = {0,0,0,0}, acc10 = {0,0,0,0};
  short8 ah0, ah1, al0, al1;
  short8 b1h[4], b1l[4];               // 4-buffer B pipeline, 1 ncol/wave

#define XSTORE(CH, BUF) do {                                            \
    const int off = (xm * 256 + xk * 2) ^ ((xm & 15) << 4);             \
    *(ushort4*)(sm + XSB(BUF) + off) = pxh[CH];                         \
    *(ushort4*)(sm + XSB(BUF) + 8192 + off) = pxl[CH];                  \
  } while (0)
#define LOADB1(F, S) do {                                               \
    const int Fc = (F) < 31 ? (F) : 31;                                 \
    const size_t o = ((size_t)(Fc * 4 + kgrp) * 256 + wv * 16 + l15) * 16; \
    b1h[S] = *(const short8*)(wc4_hi + o);                              \
    b1l[S] = *(const short8*)(wc4_lo + o);                              \
  } while (0)
  auto afrag = [&](int CB, int KS) {
    const int k0 = KS * 64 + kgrp * 16;
    const int a0 = (l15 * 256 + k0) ^ (l15 << 4);
    const int a1 = ((16 + l15) * 256 + k0) ^ (l15 << 4);
    ah0 = *(const short8*)(sm + XSB(CB) + a0);
    al0 = *(const short8*)(sm + XSB(CB) + 8192 + a0);
    ah1 = *(const short8*)(sm + XSB(CB) + a1);
    al1 = *(const short8*)(sm + XSB(CB) + 8192 + a1);
  };
#define MFMASTEP(S) do {                                                \
    acc00 = MFMA16(ah0, b1h[S], acc00);                                 \
    acc00 = MFMA16(ah0, b1l[S], acc00);                                 \
    acc00 = MFMA16(al0, b1h[S], acc00);                                 \
    acc10 = MFMA16(ah1, b1h[S], acc10);                                 \
    acc10 = MFMA16(ah1, b1l[S], acc10);                                 \
    acc10 = MFMA16(al1, b1h[S], acc10);                                 \
  } while (0)

  // prologue
  LOADB1(0, 0);
  LOADB1(1, 1);
  XSTORE(0, 0);

#pragma unroll
  for (int ch = 0; ch < 8; ++ch) {
    __syncthreads();                 // xs(ch) visible to all waves
    const int cb = ch & 1;
    const int f = ch * 4;
    LOADB1(f + 2, 2); afrag(cb, 0); MFMASTEP(0);
    LOADB1(f + 3, 3); afrag(cb, 1); MFMASTEP(1);
    LOADB1(f + 4, 0); afrag(cb, 2); MFMASTEP(2);
    LOADB1(f + 5, 1); afrag(cb, 3); MFMASTEP(3);
    if (ch < 7) XSTORE(ch + 1, cb ^ 1);   // LDS-only, from registers
  }
  __syncthreads();

  // scatter logits into act f32[32][256] (overlays xs)
  {
    float* actp = (float*)sm;
    const int col = wv * 16 + l15;
#pragma unroll
    for (int r = 0; r < 4; ++r) {
      actp[(kgrp * 4 + r) * 256 + col]      = acc00[r];
      actp[(16 + kgrp * 4 + r) * 256 + col] = acc10[r];
    }
  }
  __syncthreads();

  // GEMM2 B pipeline buffers (3-buffer, distance 2, 2 ocol-frags/wave)
  short8 c2h[3][2], c2l[3][2];
#define LOADB2(F, S) do {                                               \
    const size_t base = ((size_t)((F) * 4 + kgrp) * 512) * 16;          \
    _Pragma("unroll")                                                   \
    for (int t = 0; t < 2; ++t) {                                       \
      const size_t o = base + (size_t)(wv * 32 + t * 16 + l15) * 16;    \
      c2h[S][t] = *(const short8*)(lo4_hi + o);                         \
      c2l[S][t] = *(const short8*)(lo4_lo + o);                         \
    }                                                                   \
  } while (0)
  LOADB2(0, 0);   // issued before epilogue: L2 latency hides under VALU
  LOADB2(1, 1);

  // ================= Phase B: forest epilogue (waves 0-7) =============
  if (tid < 512) {
    const float* actp = (const float*)sm;
    const int token = tid >> 4;      // 0..31
    const int tr    = tid & 15;      // tree
    const float* arow_p = actp + token * 256;

    float dec[15];
#pragma unroll
    for (int i = 0; i < 15; ++i) {
      const int ci = tr * 15 + i;
      const float z = (arow_p[ci] + par[ci]) * par[240 + ci];
      dec[i] = 1.f / (1.f + expf(-z));
    }
    float gl = arow_p[240 + tr] + gate_b[tr];
    float gmax = gl;
#pragma unroll
    for (int msk = 8; msk >= 1; msk >>= 1) gmax = fmaxf(gmax, __shfl_xor(gmax, msk, 16));
    const float ge = expf(gl - gmax);
    float gsum = ge;
#pragma unroll
    for (int msk = 8; msk >= 1; msk >>= 1) gsum += __shfl_xor(gsum, msk, 16);
    const float gate = ge / gsum;

    float lp[16];
#pragma unroll
    for (int l = 0; l < 16; ++l) {
      float p = gate;
      int node = 0;
#pragma unroll
      for (int d = 0; d < 4; ++d) {
        const int bit = (l >> (3 - d)) & 1;
        p *= bit ? (1.f - dec[node]) : dec[node];
        node = 2 * node + 1 + bit;
      }
      lp[l] = p;
    }
    short8 h0, h1, l0, l1;
#pragma unroll
    for (int e = 0; e < 8; ++e) {
      ushort hh, ll;
      split2(lp[e], hh, ll);     h0[e] = (short)hh; l0[e] = (short)ll;
      split2(lp[8 + e], hh, ll); h1[e] = (short)hh; l1[e] = (short)ll;
    }
    const int b0 = (token * 512 + tr * 32) ^ ((token & 15) << 4);
    const int b1 = (token * 512 + tr * 32 + 16) ^ ((token & 15) << 4);
    *(short8*)(sm + WF_HI + b0) = h0;
    *(short8*)(sm + WF_HI + b1) = h1;
    *(short8*)(sm + WF_LO + b0) = l0;
    *(short8*)(sm + WF_LO + b1) = l1;
  }
  __syncthreads();

  // ================= Phase C: GEMM2 (8 steps, fully unrolled) =========
  f32x4 ac0[2], ac1[2];
#pragma unroll
  for (int t = 0; t < 2; ++t) { ac0[t] = (f32x4){0,0,0,0}; ac1[t] = (f32x4){0,0,0,0}; }
  short8 wah0, wah1, wal0, wal1;
  auto wafrag = [&](int FC) {
    const int k0 = FC * 64 + kgrp * 16;
    const int a0 = (l15 * 512 + k0) ^ (l15 << 4);
    const int a1 = ((16 + l15) * 512 + k0) ^ (l15 << 4);
    wah0 = *(const short8*)(sm + WF_HI + a0);
    wal0 = *(const short8*)(sm + WF_LO + a0);
    wah1 = *(const short8*)(sm + WF_HI + a1);
    wal1 = *(const short8*)(sm + WF_LO + a1);
  };
#define MFMA2STEP(S) do {                                               \
    _Pragma("unroll")                                                   \
    for (int t = 0; t < 2; ++t) {                                       \
      ac0[t] = MFMA16(wah0, c2h[S][t], ac0[t]);                         \
      ac0[t] = MFMA16(wah0, c2l[S][t], ac0[t]);                         \
      ac0[t] = MFMA16(wal0, c2h[S][t], ac0[t]);                         \
      ac1[t] = MFMA16(wah1, c2h[S][t], ac1[t]);                         \
      ac1[t] = MFMA16(wah1, c2l[S][t], ac1[t]);                         \
      ac1[t] = MFMA16(wal1, c2h[S][t], ac1[t]);                         \
    }                                                                   \
  } while (0)

  LOADB2(2, 2); wafrag(0); MFMA2STEP(0);
  LOADB2(3, 0); wafrag(1); MFMA2STEP(1);
  LOADB2(4, 1); wafrag(2); MFMA2STEP(2);
  LOADB2(5, 2); wafrag(3); MFMA2STEP(0);
  LOADB2(6, 0); wafrag(4); MFMA2STEP(1);
  LOADB2(7, 1); wafrag(5); MFMA2STEP(2);
  wafrag(6); MFMA2STEP(0);
  wafrag(7); MFMA2STEP(1);

  // ================= Phase D: LayerNorm (in-register) =================
  float* ps = (float*)sm;    // [32 rows][16 waves][2] f32 = 4KB (act dead)
#pragma unroll
  for (int mi = 0; mi < 2; ++mi)
#pragma unroll
    for (int r = 0; r < 4; ++r) {
      float s = 0.f, q = 0.f;
#pragma unroll
      for (int t = 0; t < 2; ++t) {
        const float v = (mi == 0) ? ac0[t][r] : ac1[t][r];
        s += v; q += v * v;
      }
#pragma unroll
      for (int msk = 8; msk >= 1; msk >>= 1) {
        s += __shfl_xor(s, msk, 16);
        q += __shfl_xor(q, msk, 16);
      }
      if (l15 == 0) {
        const int row = mi * 16 + kgrp * 4 + r;
        ps[(row * 16 + wv) * 2 + 0] = s;
        ps[(row * 16 + wv) * 2 + 1] = q;
      }
    }
  __syncthreads();

#pragma unroll
  for (int mi = 0; mi < 2; ++mi)
#pragma unroll
    for (int r = 0; r < 4; ++r) {
      const int row = mi * 16 + kgrp * 4 + r;
      float S = 0.f, Q = 0.f;
#pragma unroll
      for (int p = 0; p < 16; ++p) {
        S += ps[(row * 16 + p) * 2 + 0];
        Q += ps[(row * 16 + p) * 2 + 1];
      }
      const float mu  = S * (1.f / 512.f);
      const float var = Q * (1.f / 512.f) - mu * mu;
      const float rs  = rsqrtf(var + 1e-5f);
#pragma unroll
      for (int t = 0; t < 2; ++t) {
        const int col = wv * 32 + t * 16 + l15;
        const float v = (mi == 0) ? ac0[t][r] : ac1[t][r];
        out[(size_t)(m0 + row) * OO + col] = (v - mu) * rs * gamma[col] + beta[col];
      }
    }
}

// ---------------------------------------------------------------------------
extern "C" void kernel_launch(void* const* d_in, const int* in_sizes, int n_in,
                              void* d_out, int out_size, void* d_ws, size_t ws_size,
                              hipStream_t stream) {
  const float* x   = (const float*)d_in[0];  // (4,2048,1024)
  const float* dw  = (const float*)d_in[1];  // (16,15,1024)
  const float* db  = (const float*)d_in[2];  // (16,15)
  const float* lo  = (const float*)d_in[3];  // (16,16,512)
  const float* gw  = (const float*)d_in[4];  // (1024,16)
  const float* gb  = (const float*)d_in[5];  // (16,)
  const float* ntl = (const float*)d_in[6];  // (16,15)
  const float* g   = (const float*)d_in[7];  // (512,)
  const float* b   = (const float*)d_in[8];  // (512,)
  char* ws   = (char*)d_ws;
  float* out = (float*)d_out;

  k_prep<<<33, 1024, 0, stream>>>(dw, db, lo, gw, ntl, ws);
  k_fused<<<256, 1024, 0, stream>>>(x, ws, gb, g, b, out);
}

// Round 11
// 119.553 us; speedup vs baseline: 1.1370x; 1.0367x over previous
//
#include <hip/hip_runtime.h>
#include <math.h>

// Problem constants (B=4, S=2048, D=1024, O=512, T=16, depth=4)
#define TOK 8192
#define DD  1024
#define OO  512
#define NC  256   // 240 decision rows + 16 gate rows

// ---- workspace byte layout (~1.5MB) ----
// Wc4: [128 k8][256 ncol] 16B units (8 consecutive k as bf16 per unit)
// LO4: [32 k8][512 ocol] 16B units
#define WC4_HI 0
#define WC4_LO (512*1024)
#define LO4_HI (1024*1024)
#define LO4_LO (1280*1024)
#define PAR_B  (1536*1024)   // f32 bias[240], invt[240]

typedef __attribute__((ext_vector_type(8))) short short8;
typedef __attribute__((ext_vector_type(4))) float f32x4;

#define MFMA16(a,b,c) __builtin_amdgcn_mfma_f32_16x16x32_bf16((a),(b),(c),0,0,0)

__device__ __forceinline__ ushort f2bh(float f) {   // f32 -> bf16 RNE
  union { float f; unsigned u; } v; v.f = f;
  unsigned r = v.u + 0x7fffu + ((v.u >> 16) & 1u);
  return (ushort)(r >> 16);
}
__device__ __forceinline__ float bh2f(ushort h) {
  union { unsigned u; float f; } v; v.u = ((unsigned)h) << 16; return v.f;
}
__device__ __forceinline__ void split2(float f, ushort& h, ushort& l) {
  h = f2bh(f);
  l = f2bh(f - bh2f(h));
}

// ---------------------------------------------------------------------------
// Prep (byte-identical to round 10 for attribution): 33 blocks x 1024 thr.
// ---------------------------------------------------------------------------
__global__ __launch_bounds__(1024) void k_prep(
    const float* __restrict__ dw, const float* __restrict__ db,
    const float* __restrict__ lo_in, const float* __restrict__ gw,
    const float* __restrict__ ntl, char* __restrict__ ws) {
  const int bid = blockIdx.x, tid = threadIdx.x;
  if (bid < 16) {
    __shared__ char pt[65536];           // hi tile 32KB | lo tile 32KB
    const int n0 = (bid & 3) * 64;
    const int k0 = (bid >> 2) * 256;
    const int kl4 = (tid & 63) << 2;     // local k (floats), 0..252
#pragma unroll
    for (int i = 0; i < 4; ++i) {
      const int row = (tid >> 6) + 16 * i;   // 0..63
      const int n = n0 + row;
      float v[4];
      if (n < 240) {
        const float4 t4 = *(const float4*)&dw[(size_t)n * DD + k0 + kl4];
        v[0] = t4.x; v[1] = t4.y; v[2] = t4.z; v[3] = t4.w;
      } else {
        const int t = n - 240;
#pragma unroll
        for (int c = 0; c < 4; ++c) v[c] = gw[(size_t)(k0 + kl4 + c) * 16 + t];
      }
      ushort4 h, l;
      split2(v[0], h.x, l.x); split2(v[1], h.y, l.y);
      split2(v[2], h.z, l.z); split2(v[3], h.w, l.w);
      const int u = kl4 >> 3, half = (kl4 >> 2) & 1;
      const int boff = row * 512 + ((u ^ (row & 31)) << 4) + half * 8;
      *(ushort4*)(pt + boff) = h;
      *(ushort4*)(pt + 32768 + boff) = l;
    }
    __syncthreads();
#pragma unroll
    for (int j = 0; j < 2; ++j) {
      const int u = tid + 1024 * j;       // 0..2047
      const int c = u & 63;               // ncol-local
      const int kk = u >> 6;              // 0..31
      const int src = c * 512 + ((kk ^ (c & 31)) << 4);
      const size_t dst = ((size_t)((k0 >> 3) + kk) * 256 + n0 + c) * 16;
      *(short8*)(ws + WC4_HI + dst) = *(const short8*)(pt + src);
      *(short8*)(ws + WC4_LO + dst) = *(const short8*)(pt + 32768 + src);
    }
  } else if (bid < 32) {                 // LO: both sides coalesced
    const int idx  = (bid - 16) * 1024 + tid;   // 0..16383
    const int k8   = idx >> 9;           // 0..31
    const int ocol = idx & 511;
    float v[8];
#pragma unroll
    for (int c = 0; c < 8; ++c) v[c] = lo_in[(size_t)(k8 * 8 + c) * OO + ocol];
    short8 h, l;
#pragma unroll
    for (int e = 0; e < 8; ++e) {
      ushort hh, ll; split2(v[e], hh, ll);
      h[e] = (short)hh; l[e] = (short)ll;
    }
    const size_t o16 = ((size_t)k8 * 512 + ocol) * 16;
    *(short8*)(ws + LO4_HI + o16) = h;
    *(short8*)(ws + LO4_LO + o16) = l;
  } else {
    if (tid < 240) {
      float v = ntl[tid] + 0.5413f;
      float sp = (v > 20.f) ? v : log1pf(expf(v));   // softplus
      float* par = (float*)(ws + PAR_B);
      par[tid]       = db[tid];
      par[240 + tid] = 1.0f / sp;
    }
  }
}

// ---------------------------------------------------------------------------
// Fused MFMA kernel: block = 32 tokens, 1024 threads (16 waves), grid 256.
// NEW vs r9/r10: per-block ROTATION of the B-read order.  All 32 blocks on
// one XCD previously streamed the SAME 1.5MB L2 line sequence in lockstep
// (same-line request serialization at the XCD L2 = suspected 40us wall).
// rot=(bid>>3)&7 rotates the chunk order; r2=(bid>>6)&3 rotates the k-slice
// order within a chunk -> each resident block reads a distinct region at
// any instant.  K-summation order changes only (f32 reassociation).
// LDS 64KB: xs dbuf 2x16K (act f32[32][256]+psum overlays) | wf hi/lo 16K+16K
// ---------------------------------------------------------------------------
#define XSB(b)  ((b) * 16384)      // per-buffer: HI at +0 (8K), LO at +8192
#define WF_HI   32768
#define WF_LO   49152
#define SM_SZ   65536

__global__ __launch_bounds__(1024) void k_fused(
    const float* __restrict__ x, const char* __restrict__ ws,
    const float* __restrict__ gate_b, const float* __restrict__ gamma,
    const float* __restrict__ beta, float* __restrict__ out) {
  __shared__ __align__(16) char sm[SM_SZ];

  const char* wc4_hi = ws + WC4_HI;
  const char* wc4_lo = ws + WC4_LO;
  const char* lo4_hi = ws + LO4_HI;
  const char* lo4_lo = ws + LO4_LO;
  const float* par   = (const float*)(ws + PAR_B);

  const int tid  = threadIdx.x;        // 0..1023
  const int wv   = tid >> 6;           // 0..15
  const int lane = tid & 63;
  const int l15  = lane & 15;
  const int kgrp = lane >> 4;          // 0..3
  const int bid  = blockIdx.x;
  const int m0   = bid * 32;

  // per-block read-order rotation (uniform -> SGPR arithmetic)
  const int rot = (bid >> 3) & 7;      // chunk rotation, distinct within XCD
  const int r2  = (bid >> 6) & 3;      // intra-chunk k-slice rotation

  auto CHUNK = [&](int it) { return (it + rot) & 7; };
  auto KSLOT = [&](int p)  { return (p + r2) & 3; };
  auto FQ    = [&](int q)  { q &= 31; return CHUNK(q >> 2) * 4 + KSLOT(q & 3); };

  const int xm = tid >> 5;             // 0..31
  const int xk = (tid & 31) << 2;      // 0..124

  // ================= Phase A: GEMM1 =================
  f32x4 acc00 = {0,0,0,0}, acc10 = {0,0,0,0};
  short8 ah0, ah1, al0, al1;
  short8 b1h[4], b1l[4];               // 4-buffer B pipeline, 1 ncol/wave
  float4 px;

  auto xload = [&](int CH) {           // runtime chunk index (global addr ok)
    px = *(const float4*)&x[(size_t)(m0 + xm) * DD + CH * 128 + xk];
  };
  auto xstore = [&](int BUF) {
    ushort4 h, l;
    split2(px.x, h.x, l.x); split2(px.y, h.y, l.y);
    split2(px.z, h.z, l.z); split2(px.w, h.w, l.w);
    const int off = (xm * 256 + xk * 2) ^ ((xm & 15) << 4);
    *(ushort4*)(sm + XSB(BUF) + off) = h;
    *(ushort4*)(sm + XSB(BUF) + 8192 + off) = l;
  };
#define LOADB1(F, S) do {                                               \
    const size_t o = ((size_t)((F) * 4 + kgrp) * 256 + wv * 16 + l15) * 16; \
    b1h[S] = *(const short8*)(wc4_hi + o);                              \
    b1l[S] = *(const short8*)(wc4_lo + o);                              \
  } while (0)
  auto afrag = [&](int CB, int KS) {   // runtime KS ok (LDS addr arithmetic)
    const int k0 = KS * 64 + kgrp * 16;
    const int a0 = (l15 * 256 + k0) ^ (l15 << 4);
    const int a1 = ((16 + l15) * 256 + k0) ^ (l15 << 4);
    ah0 = *(const short8*)(sm + XSB(CB) + a0);
    al0 = *(const short8*)(sm + XSB(CB) + 8192 + a0);
    ah1 = *(const short8*)(sm + XSB(CB) + a1);
    al1 = *(const short8*)(sm + XSB(CB) + 8192 + a1);
  };
#define MFMASTEP(S) do {                                                \
    acc00 = MFMA16(ah0, b1h[S], acc00);                                 \
    acc00 = MFMA16(ah0, b1l[S], acc00);                                 \
    acc00 = MFMA16(al0, b1h[S], acc00);                                 \
    acc10 = MFMA16(ah1, b1h[S], acc10);                                 \
    acc10 = MFMA16(ah1, b1l[S], acc10);                                 \
    acc10 = MFMA16(al1, b1h[S], acc10);                                 \
  } while (0)

  // prologue (rotated order)
  xload(CHUNK(0));
  xstore(0);
  LOADB1(FQ(0), 0);
  LOADB1(FQ(1), 1);

#pragma unroll
  for (int it = 0; it < 8; ++it) {
    __syncthreads();                 // xs(chunk it) visible to all waves
    const int cb = it & 1;
    if (it < 7) xload(CHUNK(it + 1));   // HBM prefetch, hides under MFMAs
    const int q = it * 4;
    LOADB1(FQ(q + 2), 2); afrag(cb, KSLOT(0)); MFMASTEP(0);
    LOADB1(FQ(q + 3), 3); afrag(cb, KSLOT(1)); MFMASTEP(1);
    LOADB1(FQ(q + 4), 0); afrag(cb, KSLOT(2)); MFMASTEP(2);
    LOADB1(FQ(q + 5), 1); afrag(cb, KSLOT(3)); MFMASTEP(3);
    if (it < 7) xstore(cb ^ 1);      // write NEXT buffer
  }
  __syncthreads();

  // scatter logits into act f32[32][256] (overlays xs)
  {
    float* actp = (float*)sm;
    const int col = wv * 16 + l15;
#pragma unroll
    for (int r = 0; r < 4; ++r) {
      actp[(kgrp * 4 + r) * 256 + col]      = acc00[r];
      actp[(16 + kgrp * 4 + r) * 256 + col] = acc10[r];
    }
  }
  __syncthreads();

  // GEMM2 B pipeline buffers (3-buffer, distance 2, rotated step order)
  short8 c2h[3][2], c2l[3][2];
#define LOADB2(F, S) do {                                               \
    const size_t base = ((size_t)((F) * 4 + kgrp) * 512) * 16;          \
    _Pragma("unroll")                                                   \
    for (int t = 0; t < 2; ++t) {                                       \
      const size_t o = base + (size_t)(wv * 32 + t * 16 + l15) * 16;    \
      c2h[S][t] = *(const short8*)(lo4_hi + o);                         \
      c2l[S][t] = *(const short8*)(lo4_lo + o);                         \
    }                                                                   \
  } while (0)
  auto F2 = [&](int s) { return (s + rot) & 7; };
  LOADB2(F2(0), 0);   // issued before epilogue: latency hides under VALU
  LOADB2(F2(1), 1);

  // ================= Phase B: forest epilogue (waves 0-7) =============
  if (tid < 512) {
    const float* actp = (const float*)sm;
    const int token = tid >> 4;      // 0..31
    const int tr    = tid & 15;      // tree
    const float* arow_p = actp + token * 256;

    float dec[15];
#pragma unroll
    for (int i = 0; i < 15; ++i) {
      const int ci = tr * 15 + i;
      const float z = (arow_p[ci] + par[ci]) * par[240 + ci];
      dec[i] = 1.f / (1.f + expf(-z));
    }
    float gl = arow_p[240 + tr] + gate_b[tr];
    float gmax = gl;
#pragma unroll
    for (int msk = 8; msk >= 1; msk >>= 1) gmax = fmaxf(gmax, __shfl_xor(gmax, msk, 16));
    const float ge = expf(gl - gmax);
    float gsum = ge;
#pragma unroll
    for (int msk = 8; msk >= 1; msk >>= 1) gsum += __shfl_xor(gsum, msk, 16);
    const float gate = ge / gsum;

    float lp[16];
#pragma unroll
    for (int l = 0; l < 16; ++l) {
      float p = gate;
      int node = 0;
#pragma unroll
      for (int d = 0; d < 4; ++d) {
        const int bit = (l >> (3 - d)) & 1;
        p *= bit ? (1.f - dec[node]) : dec[node];
        node = 2 * node + 1 + bit;
      }
      lp[l] = p;
    }
    short8 h0, h1, l0, l1;
#pragma unroll
    for (int e = 0; e < 8; ++e) {
      ushort hh, ll;
      split2(lp[e], hh, ll);     h0[e] = (short)hh; l0[e] = (short)ll;
      split2(lp[8 + e], hh, ll); h1[e] = (short)hh; l1[e] = (short)ll;
    }
    const int b0 = (token * 512 + tr * 32) ^ ((token & 15) << 4);
    const int b1 = (token * 512 + tr * 32 + 16) ^ ((token & 15) << 4);
    *(short8*)(sm + WF_HI + b0) = h0;
    *(short8*)(sm + WF_HI + b1) = h1;
    *(short8*)(sm + WF_LO + b0) = l0;
    *(short8*)(sm + WF_LO + b1) = l1;
  }
  __syncthreads();

  // ================= Phase C: GEMM2 (8 steps, rotated, unrolled) ======
  f32x4 ac0[2], ac1[2];
#pragma unroll
  for (int t = 0; t < 2; ++t) { ac0[t] = (f32x4){0,0,0,0}; ac1[t] = (f32x4){0,0,0,0}; }
  short8 wah0, wah1, wal0, wal1;
  auto wafrag = [&](int FC) {          // runtime FC ok (LDS addr arithmetic)
    const int k0 = FC * 64 + kgrp * 16;
    const int a0 = (l15 * 512 + k0) ^ (l15 << 4);
    const int a1 = ((16 + l15) * 512 + k0) ^ (l15 << 4);
    wah0 = *(const short8*)(sm + WF_HI + a0);
    wal0 = *(const short8*)(sm + WF_LO + a0);
    wah1 = *(const short8*)(sm + WF_HI + a1);
    wal1 = *(const short8*)(sm + WF_LO + a1);
  };
#define MFMA2STEP(S) do {                                               \
    _Pragma("unroll")                                                   \
    for (int t = 0; t < 2; ++t) {                                       \
      ac0[t] = MFMA16(wah0, c2h[S][t], ac0[t]);                         \
      ac0[t] = MFMA16(wah0, c2l[S][t], ac0[t]);                         \
      ac0[t] = MFMA16(wal0, c2h[S][t], ac0[t]);                         \
      ac1[t] = MFMA16(wah1, c2h[S][t], ac1[t]);                         \
      ac1[t] = MFMA16(wah1, c2l[S][t], ac1[t]);                         \
      ac1[t] = MFMA16(wal1, c2h[S][t], ac1[t]);                         \
    }                                                                   \
  } while (0)

  LOADB2(F2(2), 2); wafrag(F2(0)); MFMA2STEP(0);
  LOADB2(F2(3), 0); wafrag(F2(1)); MFMA2STEP(1);
  LOADB2(F2(4), 1); wafrag(F2(2)); MFMA2STEP(2);
  LOADB2(F2(5), 2); wafrag(F2(3)); MFMA2STEP(0);
  LOADB2(F2(6), 0); wafrag(F2(4)); MFMA2STEP(1);
  LOADB2(F2(7), 1); wafrag(F2(5)); MFMA2STEP(2);
  wafrag(F2(6)); MFMA2STEP(0);
  wafrag(F2(7)); MFMA2STEP(1);

  // ================= Phase D: LayerNorm (in-register) =================
  float* ps = (float*)sm;    // [32 rows][16 waves][2] f32 = 4KB (act dead)
#pragma unroll
  for (int mi = 0; mi < 2; ++mi)
#pragma unroll
    for (int r = 0; r < 4; ++r) {
      float s = 0.f, q = 0.f;
#pragma unroll
      for (int t = 0; t < 2; ++t) {
        const float v = (mi == 0) ? ac0[t][r] : ac1[t][r];
        s += v; q += v * v;
      }
#pragma unroll
      for (int msk = 8; msk >= 1; msk >>= 1) {
        s += __shfl_xor(s, msk, 16);
        q += __shfl_xor(q, msk, 16);
      }
      if (l15 == 0) {
        const int row = mi * 16 + kgrp * 4 + r;
        ps[(row * 16 + wv) * 2 + 0] = s;
        ps[(row * 16 + wv) * 2 + 1] = q;
      }
    }
  __syncthreads();

#pragma unroll
  for (int mi = 0; mi < 2; ++mi)
#pragma unroll
    for (int r = 0; r < 4; ++r) {
      const int row = mi * 16 + kgrp * 4 + r;
      float S = 0.f, Q = 0.f;
#pragma unroll
      for (int p = 0; p < 16; ++p) {
        S += ps[(row * 16 + p) * 2 + 0];
        Q += ps[(row * 16 + p) * 2 + 1];
      }
      const float mu  = S * (1.f / 512.f);
      const float var = Q * (1.f / 512.f) - mu * mu;
      const float rs  = rsqrtf(var + 1e-5f);
#pragma unroll
      for (int t = 0; t < 2; ++t) {
        const int col = wv * 32 + t * 16 + l15;
        const float v = (mi == 0) ? ac0[t][r] : ac1[t][r];
        out[(size_t)(m0 + row) * OO + col] = (v - mu) * rs * gamma[col] + beta[col];
      }
    }
}

// ---------------------------------------------------------------------------
extern "C" void kernel_launch(void* const* d_in, const int* in_sizes, int n_in,
                              void* d_out, int out_size, void* d_ws, size_t ws_size,
                              hipStream_t stream) {
  const float* x   = (const float*)d_in[0];  // (4,2048,1024)
  const float* dw  = (const float*)d_in[1];  // (16,15,1024)
  const float* db  = (const float*)d_in[2];  // (16,15)
  const float* lo  = (const float*)d_in[3];  // (16,16,512)
  const float* gw  = (const float*)d_in[4];  // (1024,16)
  const float* gb  = (const float*)d_in[5];  // (16,)
  const float* ntl = (const float*)d_in[6];  // (16,15)
  const float* g   = (const float*)d_in[7];  // (512,)
  const float* b   = (const float*)d_in[8];  // (512,)
  char* ws   = (char*)d_ws;
  float* out = (float*)d_out;

  k_prep<<<33, 1024, 0, stream>>>(dw, db, lo, gw, ntl, ws);
  k_fused<<<256, 1024, 0, stream>>>(x, ws, gb, g, b, out);
}